// Round 4
// baseline (443.370 us; speedup 1.0000x reference)
//
#include <hip/hip_runtime.h>
#include <cstdint>
#include <cstddef>

typedef __attribute__((ext_vector_type(4))) float f32x4;
typedef __attribute__((ext_vector_type(8))) __bf16 bf16x8;
typedef __attribute__((ext_vector_type(8))) unsigned short u16x8;

__device__ __forceinline__ unsigned short f2bf(float f) {
  unsigned int u = __builtin_bit_cast(unsigned int, f);
  u = (u + 0x7FFFu + ((u >> 16) & 1u)) >> 16;
  return (unsigned short)u;
}
__device__ __forceinline__ float bf2f(unsigned short b) {
  return __builtin_bit_cast(float, ((unsigned int)b) << 16);
}

// async global->LDS, 16B/lane; LDS dest = wave-uniform base + lane*16.
__device__ __forceinline__ void async_copy16(const void* g, void* l) {
  __builtin_amdgcn_global_load_lds(
      (__attribute__((address_space(1))) void*)(g),
      (__attribute__((address_space(3))) void*)(l), 16, 0, 0);
}

// ---------------------------------------------------------------------------
// 256x256-tile, BK=64, 8-wave (2Mx4N), 4-phase counted-vmcnt GEMM.
// C[m][n] = alpha * sum_k A[m][k]*Bt[n][k] (+ bias). BIAS_MODE: 0 none,
// 1 per-col (bias[z*sbiasz + n]), 2 per-row. Grid (N/256, M/256, Z), element
// strides sAz/sBz/sCz. M%256==N%256==0, K%64==0, K>=192.
// Grid constraint for the tile remap: (gx*gy)%8==0 and gy%4==0.
//
// Tile remap (T1 + GROUP_M supertile): linear block id within the z-slice is
// remapped so each XCD (id%8 under round-robin dispatch) processes a
// CONTIGUOUS chunk of tiles, walked in 4-row x gx-col supertiles -> the Q/K
// panels a chunk touches (~6MB) mostly L2-hit instead of thrashing 8 XCD L2s.
//
// LDS 128 KiB: buf{0,1} x (A[256][64] | B[256][64]) bf16, row stride 128B.
// Swizzle: 16B-slot s XOR (row&7) on the *global source* at staging (linear
// LDS dest, rule #21) and on the ds_read_b128 address (round-1: 0 conflicts).
//
// Per-tile phases (16 MFMA each; B register-resident whole tile, A-quadrant
// resident 2 phases; reads/phase {12,4,8,0}):
//   p1 (0,0): read A-q0 (8) + B-q0 (4);  stage A-chunk1(t+1) -> idle buf
//   p2 (0,1): read B-q1 (4);             stage B-chunk1(t+1) -> idle buf
//   p3 (1,1): read A-q1 (8, overwrite);  stage A-chunk0(t+2) -> LIVE buf
//   p4 (1,0): no reads (regs only);      stage B-chunk0(t+2) -> LIVE buf
// Deadness: A-chunk0 LDS rows last read p1 (stage p3: 1 barrier-pair later);
// B-chunk0 LDS rows last read p1 (regs thereafter; stage p4). vmcnt(4) once
// per tile at p4: 12 outstanding -> completes 8 oldest = all of tile t+1.
// Tail (t+2>=NT): drain to 0.
// ---------------------------------------------------------------------------
template <int BIAS_MODE, bool OUT_BF16>
__global__ __launch_bounds__(512, 1) void gemm256(
    const unsigned short* __restrict__ A, const unsigned short* __restrict__ Bt,
    const float* __restrict__ bias, void* __restrict__ Cout,
    int K, int lda, int ldb, int ldc, float alpha,
    size_t sAz, size_t sBz, size_t sCz, size_t sbiasz)
{
  __shared__ __align__(16) char lds[131072];

  const int tid = threadIdx.x;
  const int w = tid >> 6, lane = tid & 63;
  const int wm = w >> 2, wn = w & 3;
  const int l15 = lane & 15, q = lane >> 4, s7 = lane & 7;

  // ---- tile remap: XCD-chunk + 4-row supertile (see header) ----
  const int gx = gridDim.x;
  const int nwg = gx * gridDim.y;
  const int bid0 = blockIdx.y * gx + blockIdx.x;
  const int nid = (bid0 & 7) * (nwg >> 3) + (bid0 >> 3);  // nwg%8==0
  const int gsz = 4 * gx;                                  // gy%4==0
  const int ing = nid % gsz;
  const int by2 = (nid / gsz) * 4 + (ing & 3);
  const int bx2 = ing >> 2;
  const int m0 = by2 * 256, n0 = bx2 * 256;

  A  += (size_t)blockIdx.z * sAz;
  Bt += (size_t)blockIdx.z * sBz;
  if (BIAS_MODE) bias += (size_t)blockIdx.z * sbiasz;

  // staging: each instr covers 8 rows x 8 swizzled 16B slots
  const int srow = lane >> 3;
  const int sslot = s7 ^ srow;  // pre-swizzled global 16B slot
  const unsigned short* aS = A + (size_t)(m0 + srow) * lda + sslot * 8;
  const unsigned short* bS = Bt + (size_t)(n0 + srow) * ldb + sslot * 8;
  const int arb = (w >> 2) * 128 + (w & 3) * 16;  // A: + c*64 + {0,8}
  const int brb = (w >> 1) * 64 + (w & 1) * 16;   // B: + c*32 + {0,8}

  const int wmB = wm * 128, wnB = wn * 64;

#define LDSA(buf) (lds + (buf) * 65536)
#define LDSB(buf) (lds + (buf) * 65536 + 32768)

#define STAGE_A(c, kt, buf) do { \
    async_copy16(aS + (size_t)(arb + (c)*64) * lda + (kt),     LDSA(buf) + (arb + (c)*64) * 128); \
    async_copy16(aS + (size_t)(arb + (c)*64 + 8) * lda + (kt), LDSA(buf) + (arb + (c)*64 + 8) * 128); \
  } while (0)
#define STAGE_B(c, kt, buf) do { \
    async_copy16(bS + (size_t)(brb + (c)*32) * ldb + (kt),     LDSB(buf) + (brb + (c)*32) * 128); \
    async_copy16(bS + (size_t)(brb + (c)*32 + 8) * ldb + (kt), LDSB(buf) + (brb + (c)*32 + 8) * 128); \
  } while (0)

#define READ_A(QM) do { _Pragma("unroll") for (int i = 0; i < 4; ++i) { \
      const int ro = (wmB + (QM)*64 + i*16 + l15) * 128; \
      _Pragma("unroll") for (int kk = 0; kk < 2; ++kk) \
        afr[i][kk] = *(const bf16x8*)(Ab + ro + (((kk*4 + q) ^ s7) * 16)); } } while (0)
#define READ_B(QN) do { _Pragma("unroll") for (int j = 0; j < 2; ++j) { \
      const int ro = (wnB + (QN)*32 + j*16 + l15) * 128; \
      _Pragma("unroll") for (int kk = 0; kk < 2; ++kk) \
        bfr[(QN)*2 + j][kk] = *(const bf16x8*)(Bb + ro + (((kk*4 + q) ^ s7) * 16)); } } while (0)
#define MFMA_Q(QM, QN) do { _Pragma("unroll") for (int i = 0; i < 4; ++i) \
      _Pragma("unroll") for (int j = 0; j < 2; ++j) \
      _Pragma("unroll") for (int kk = 0; kk < 2; ++kk) \
        acc[(QM)*4+i][(QN)*2+j] = __builtin_amdgcn_mfma_f32_16x16x32_bf16( \
            afr[i][kk], bfr[(QN)*2+j][kk], acc[(QM)*4+i][(QN)*2+j], 0, 0, 0); } while (0)

  const int NT = K >> 6;
  f32x4 acc[8][4] = {};
  bf16x8 afr[4][2];   // current A quadrant (overwritten in p3)
  bf16x8 bfr[4][2];   // ALL of B, resident across the whole tile

  // prologue: tile0 fully + tile1 {A-chunk0, B-chunk0} into buf1
  STAGE_A(0, 0, 0); STAGE_A(1, 0, 0);
  STAGE_B(0, 0, 0); STAGE_B(1, 0, 0);
  STAGE_A(0, 64, 1); STAGE_B(0, 64, 1);
  asm volatile("s_waitcnt vmcnt(4)" ::: "memory");  // tile0's 8 landed
  __builtin_amdgcn_s_barrier();

  for (int t = 0; t < NT; ++t) {
    const char* Ab = LDSA(t & 1);
    const char* Bb = LDSB(t & 1);
    const int kt1 = (t + 1) << 6, kt2 = (t + 2) << 6;
    const bool s1 = (t + 1 < NT), s2 = (t + 2 < NT);

    // p1 (0,0)
    READ_A(0); READ_B(0);
    if (s1) STAGE_A(1, kt1, (t + 1) & 1);
    __builtin_amdgcn_s_barrier();
    __builtin_amdgcn_s_setprio(1); MFMA_Q(0, 0); __builtin_amdgcn_s_setprio(0);
    __builtin_amdgcn_s_barrier();

    // p2 (0,1)
    READ_B(1);
    if (s1) STAGE_B(1, kt1, (t + 1) & 1);
    __builtin_amdgcn_s_barrier();
    __builtin_amdgcn_s_setprio(1); MFMA_Q(0, 1); __builtin_amdgcn_s_setprio(0);
    __builtin_amdgcn_s_barrier();

    // p3 (1,1)
    READ_A(1);
    if (s2) STAGE_A(0, kt2, t & 1);   // A-chunk0 dead after p1
    __builtin_amdgcn_s_barrier();
    __builtin_amdgcn_s_setprio(1); MFMA_Q(1, 1); __builtin_amdgcn_s_setprio(0);
    __builtin_amdgcn_s_barrier();

    // p4 (1,0) — pure register MFMA
    if (s2) STAGE_B(0, kt2, t & 1);   // B-chunk0 in regs since p1
    __builtin_amdgcn_s_barrier();
    __builtin_amdgcn_s_setprio(1); MFMA_Q(1, 0); __builtin_amdgcn_s_setprio(0);
    if (s2) asm volatile("s_waitcnt vmcnt(4)" ::: "memory");  // tile t+1 landed
    else    asm volatile("s_waitcnt vmcnt(0)" ::: "memory");  // tail drain
    __builtin_amdgcn_s_barrier();
  }

  // epilogue: C/D frag layout col = lane&15, row = (lane>>4)*4 + reg
  char* Cb = (char*)Cout + (size_t)blockIdx.z * sCz * (OUT_BF16 ? 2 : 4);
#pragma unroll
  for (int mi = 0; mi < 8; ++mi) {
#pragma unroll
    for (int nj = 0; nj < 4; ++nj) {
      const int row0 = m0 + wmB + mi * 16 + q * 4;
      const int col  = n0 + wnB + nj * 16 + l15;
      float cb = (BIAS_MODE == 1) ? bias[col] : 0.0f;
#pragma unroll
      for (int r = 0; r < 4; ++r) {
        float v = acc[mi][nj][r] * alpha + cb;
        if (BIAS_MODE == 2) v += bias[row0 + r];
        const size_t idx = (size_t)(row0 + r) * ldc + col;
        if (OUT_BF16) ((unsigned short*)Cb)[idx] = f2bf(v);
        else          ((float*)Cb)[idx] = v;
      }
    }
  }
#undef LDSA
#undef LDSB
#undef STAGE_A
#undef STAGE_B
#undef READ_A
#undef READ_B
#undef MFMA_Q
}

// ---------------------------------------------------------------------------
// fp32 -> bf16 elementwise convert
// ---------------------------------------------------------------------------
__global__ __launch_bounds__(256) void convert_f32_bf16(
    const float* __restrict__ x, unsigned short* __restrict__ y, int n4)
{
  int i = blockIdx.x * blockDim.x + threadIdx.x;
  const int stride = gridDim.x * blockDim.x;
  for (; i < n4; i += stride) {
    float4 v = ((const float4*)x)[i];
    ushort4 o;
    o.x = f2bf(v.x); o.y = f2bf(v.y); o.z = f2bf(v.z); o.w = f2bf(v.w);
    ((ushort4*)y)[i] = o;
  }
}

// ---------------------------------------------------------------------------
// W[1024][1024] fp32 -> WT[1024][1024] bf16 (transpose)
// ---------------------------------------------------------------------------
__global__ __launch_bounds__(256) void transpose_to_bf16(
    const float* __restrict__ W0, const float* __restrict__ W1, const float* __restrict__ W2,
    unsigned short* __restrict__ T0, unsigned short* __restrict__ T1, unsigned short* __restrict__ T2)
{
  __shared__ float tile[64][65];
  const float* W = (blockIdx.z == 0) ? W0 : (blockIdx.z == 1) ? W1 : W2;
  unsigned short* T = (blockIdx.z == 0) ? T0 : (blockIdx.z == 1) ? T1 : T2;
  const int tx = threadIdx.x;  // 0..63
  const int ty = threadIdx.y;  // 0..3
  const int n0 = blockIdx.x * 64, k0 = blockIdx.y * 64;
#pragma unroll
  for (int r = ty; r < 64; r += 4)
    tile[r][tx] = W[(size_t)(k0 + r) * 1024 + n0 + tx];
  __syncthreads();
#pragma unroll
  for (int r = ty; r < 64; r += 4)
    T[(size_t)(n0 + r) * 1024 + k0 + tx] = f2bf(tile[tx][r]);
}

// ---------------------------------------------------------------------------
// In-place row softmax over bf16 rows of length 4096 (1 block / row)
// ---------------------------------------------------------------------------
__global__ __launch_bounds__(256) void softmax_rows(unsigned short* __restrict__ S, int ncols)
{
  __shared__ float red[8];
  unsigned short* p = S + (size_t)blockIdx.x * ncols;
  const int tid = threadIdx.x;

  u16x8 r0 = ((const u16x8*)p)[tid * 2];
  u16x8 r1 = ((const u16x8*)p)[tid * 2 + 1];
  float v[16];
#pragma unroll
  for (int i = 0; i < 8; ++i) v[i] = bf2f(r0[i]);
#pragma unroll
  for (int i = 0; i < 8; ++i) v[8 + i] = bf2f(r1[i]);

  float m = -1e30f;
#pragma unroll
  for (int i = 0; i < 16; ++i) m = fmaxf(m, v[i]);
#pragma unroll
  for (int off = 32; off; off >>= 1) m = fmaxf(m, __shfl_xor(m, off));
  if ((tid & 63) == 0) red[tid >> 6] = m;
  __syncthreads();
  m = fmaxf(fmaxf(red[0], red[1]), fmaxf(red[2], red[3]));

  float s = 0.0f;
#pragma unroll
  for (int i = 0; i < 16; ++i) {
    v[i] = exp2f((v[i] - m) * 1.44269504088896f);
    s += v[i];
  }
#pragma unroll
  for (int off = 32; off; off >>= 1) s += __shfl_xor(s, off);
  if ((tid & 63) == 0) red[4 + (tid >> 6)] = s;
  __syncthreads();
  s = red[4] + red[5] + red[6] + red[7];
  const float inv = 1.0f / s;

  u16x8 o0, o1;
#pragma unroll
  for (int i = 0; i < 8; ++i) o0[i] = f2bf(v[i] * inv);
#pragma unroll
  for (int i = 0; i < 8; ++i) o1[i] = f2bf(v[8 + i] * inv);
  ((u16x8*)p)[tid * 2] = o0;
  ((u16x8*)p)[tid * 2 + 1] = o1;
}

// ---------------------------------------------------------------------------
// Orchestration. x:[4,4096,1024]f32, W*:[1024,1024]f32, b*:[1024]f32,
// out:[4,4096,1024]f32.
//
// Batched path (ws >= 224 MB):
//   WT @0 (6.29MB) and Xb @6291456 (32MB) sit INSIDE the S_all region (dead
//   after projections). biasQK (8KB f32[2][1024]) @39845888 (also inside).
//   S_all @0 (128MB), Qb @134217728, Kb @167772160 (contig: sCz=16777216
//   elem), VTb @201326592; total 234,881,024 B.
// Fallback (ws >= 174,063,616 B): per-batch S; separate Q/K projections.
// ---------------------------------------------------------------------------
extern "C" void kernel_launch(void* const* d_in, const int* in_sizes, int n_in,
                              void* d_out, int out_size, void* d_ws, size_t ws_size,
                              hipStream_t stream) {
  (void)in_sizes; (void)n_in; (void)out_size;
  const float* x  = (const float*)d_in[0];
  const float* Wq = (const float*)d_in[1];
  const float* bq = (const float*)d_in[2];
  const float* Wk = (const float*)d_in[3];
  const float* bk = (const float*)d_in[4];
  const float* Wv = (const float*)d_in[5];
  const float* bv = (const float*)d_in[6];
  float* out = (float*)d_out;
  char* ws = (char*)d_ws;

  const bool batched = ws_size >= 234881024ull;

  unsigned short *WqT, *WkT, *WvT, *Xb, *Qb, *Kb, *VTb, *Sall = nullptr, *Sb = nullptr;
  float* biasQK = nullptr;
  if (batched) {
    WqT = (unsigned short*)(ws);
    WkT = WqT + 1048576; WvT = WkT + 1048576;
    Xb  = (unsigned short*)(ws + 6291456);
    biasQK = (float*)(ws + 39845888);
    Sall = (unsigned short*)(ws);
    Qb  = (unsigned short*)(ws + 134217728);
    Kb  = (unsigned short*)(ws + 167772160);
    VTb = (unsigned short*)(ws + 201326592);
  } else {
    WqT = (unsigned short*)(ws);
    WkT = WqT + 1048576; WvT = WkT + 1048576;
    Qb  = (unsigned short*)(ws + 6291456);
    Kb  = (unsigned short*)(ws + 39845888);
    VTb = (unsigned short*)(ws + 73400320);
    Xb  = (unsigned short*)(ws + 106954752);
    Sb  = (unsigned short*)(ws + 140509184);
  }

  // 1) precision conversion / weight transpose
  convert_f32_bf16<<<2048, 256, 0, stream>>>(x, Xb, 4194304);
  transpose_to_bf16<<<dim3(16, 16, 3), dim3(64, 4), 0, stream>>>(Wq, Wk, Wv, WqT, WkT, WvT);

  // 2) projections (K=1024)
  if (batched) {
    hipMemcpyAsync(biasQK,        bq, 4096, hipMemcpyDeviceToDevice, stream);
    hipMemcpyAsync(biasQK + 1024, bk, 4096, hipMemcpyDeviceToDevice, stream);
    // fused Q,K projection: z picks {Wq->Qb, Wk->Kb}, 512 blocks
    gemm256<1, true><<<dim3(4, 64, 2), 512, 0, stream>>>(Xb, WqT, biasQK, Qb,
        1024, 1024, 1024, 1024, 1.0f, 0, 1048576, 16777216, 1024);
  } else {
    gemm256<1, true><<<dim3(4, 64, 1), 512, 0, stream>>>(Xb, WqT, bq, Qb,
        1024, 1024, 1024, 1024, 1.0f, 0, 0, 0, 0);
    gemm256<1, true><<<dim3(4, 64, 1), 512, 0, stream>>>(Xb, WkT, bk, Kb,
        1024, 1024, 1024, 1024, 1.0f, 0, 0, 0, 0);
  }
  // V pre-transposed: VT[h][s] = sum_d WvT[h][d] X[s][d] + bv[h] (row-bias)
  gemm256<2, true><<<dim3(64, 4, 1), 512, 0, stream>>>(WvT, Xb, bv, VTb,
      1024, 1024, 1024, 16384, 1.0f, 0, 0, 0, 0);

  if (batched) {
    // 3) S = Q K^T / 32, all batches (1024 blocks)
    gemm256<0, true><<<dim3(16, 16, 4), 512, 0, stream>>>(Qb, Kb, nullptr, Sall,
        1024, 1024, 1024, 4096, 0.03125f, 4194304, 4194304, 16777216, 0);
    // 4) softmax over all 16384 rows
    softmax_rows<<<16384, 256, 0, stream>>>(Sall, 4096);
    // 5) O = P V, all batches (256 blocks)
    gemm256<0, false><<<dim3(4, 16, 4), 512, 0, stream>>>(Sall, VTb, nullptr, out,
        4096, 4096, 16384, 1024, 1.0f, 16777216, 4096, 4194304, 0);
  } else {
    for (int b = 0; b < 4; ++b) {
      const size_t qoff = (size_t)b * 4194304;
      gemm256<0, true><<<dim3(16, 16, 1), 512, 0, stream>>>(Qb + qoff, Kb + qoff, nullptr, Sb,
          1024, 1024, 1024, 4096, 0.03125f, 0, 0, 0, 0);
      softmax_rows<<<4096, 256, 0, stream>>>(Sb, 4096);
      gemm256<0, false><<<dim3(4, 16, 1), 512, 0, stream>>>(Sb, VTb + (size_t)b * 4096, nullptr, out + qoff,
          4096, 4096, 16384, 1024, 1.0f, 0, 0, 0, 0);
    }
  }
}

// Round 5
// 422.133 us; speedup vs baseline: 1.0503x; 1.0503x over previous
//
#include <hip/hip_runtime.h>
#include <cstdint>
#include <cstddef>

typedef __attribute__((ext_vector_type(4))) float f32x4;
typedef __attribute__((ext_vector_type(8))) __bf16 bf16x8;
typedef __attribute__((ext_vector_type(8))) unsigned short u16x8;

__device__ __forceinline__ unsigned short f2bf(float f) {
  unsigned int u = __builtin_bit_cast(unsigned int, f);
  u = (u + 0x7FFFu + ((u >> 16) & 1u)) >> 16;
  return (unsigned short)u;
}
__device__ __forceinline__ float bf2f(unsigned short b) {
  return __builtin_bit_cast(float, ((unsigned int)b) << 16);
}

// async global->LDS, 16B/lane; LDS dest = wave-uniform base + lane*16.
__device__ __forceinline__ void async_copy16(const void* g, void* l) {
  __builtin_amdgcn_global_load_lds(
      (__attribute__((address_space(1))) void*)(g),
      (__attribute__((address_space(3))) void*)(l), 16, 0, 0);
}

// ---------------------------------------------------------------------------
// 256x256-tile, BK=64, 8-wave (2Mx4N), 4-phase counted-vmcnt GEMM with
// ZERO-EXTRA-REGISTER READ-AHEAD: every phase's MFMA operands are ds_read
// >=1 phase before use; freed register slots are refilled by post-MFMA reads
// (WAR on the same arrays keeps VGPR at ~120; 128 AGPR acc -> 248/256 budget,
// 2 waves/SIMD preserved).
//
// C[m][n] = alpha * sum_k A[m][k]*Bt[n][k] (+ bias). BIAS_MODE: 0 none,
// 1 per-col (bias[z*sbiasz+n]), 2 per-row. Grid (N/256, M/256, Z); element
// strides sAz/sBz/sCz. M%256==N%256==0, K%64==0, NT=K/64>=2.
// Grid constraint for the tile remap: (gx*gy)%8==0 and gy%4==0.
//
// Tile remap (T1 + 4-row supertile): each XCD gets a contiguous chunk of
// tiles (round-4 measured: QK FETCH 147->98MB).
//
// LDS 128 KiB: buf{0,1} x (A[256][64] | B[256][64]) bf16, row stride 128B.
// Swizzle: 16B-slot s XOR (row&7) on the global source at staging (linear
// LDS dest, rule #21) and on the ds_read_b128 address (0 bank conflicts).
//
// Per-tile schedule (16 MFMA/phase; A-quad regs 32 + B both quads 32 VGPR):
//   p1: pre-read B1(t)->bfr[2..3]; stage A1,B1(t+1)->idle; bar;
//       MFMA(A0,B0) [regs from p4(t-1)-post]; bar.
//   p2: stage A0(t+2)->live buf [A-q0 dead: last read p4(t-1)]; bar;
//       MFMA(A0,B1); post-read A1(t)->afr; bar.
//   p3: stage B0(t+2)->live buf [B-q0 dead: last read p4(t-1)]; bar;
//       MFMA(A1,B1); vmcnt(4) [12 in flight -> completes ALL of tile t+1,
//       keeps {A0,B0}(t+2)]; bar.
//   p4: MFMA(A1,B0) [all-resident, zero lgkm];
//       post-read A0,B0(t+1) from buf[t+1]; bar.
// Stage->read separation >=2 barriers everywhere; reads of buf[t+1] occur
// after p3's vmcnt+barrier (all waves' loads complete). Accumulation order
// identical to round 4 -> bit-identical output.
// ---------------------------------------------------------------------------
template <int BIAS_MODE, bool OUT_BF16>
__global__ __launch_bounds__(512, 1) void gemm256(
    const unsigned short* __restrict__ A, const unsigned short* __restrict__ Bt,
    const float* __restrict__ bias, void* __restrict__ Cout,
    int K, int lda, int ldb, int ldc, float alpha,
    size_t sAz, size_t sBz, size_t sCz, size_t sbiasz)
{
  __shared__ __align__(16) char lds[131072];

  const int tid = threadIdx.x;
  const int w = tid >> 6, lane = tid & 63;
  const int wm = w >> 2, wn = w & 3;
  const int l15 = lane & 15, q = lane >> 4, s7 = lane & 7;

  // ---- tile remap: XCD-chunk + 4-row supertile ----
  const int gx = gridDim.x;
  const int nwg = gx * gridDim.y;
  const int bid0 = blockIdx.y * gx + blockIdx.x;
  const int nid = (bid0 & 7) * (nwg >> 3) + (bid0 >> 3);  // nwg%8==0
  const int gsz = 4 * gx;                                  // gy%4==0
  const int ing = nid % gsz;
  const int by2 = (nid / gsz) * 4 + (ing & 3);
  const int bx2 = ing >> 2;
  const int m0 = by2 * 256, n0 = bx2 * 256;

  A  += (size_t)blockIdx.z * sAz;
  Bt += (size_t)blockIdx.z * sBz;
  if (BIAS_MODE) bias += (size_t)blockIdx.z * sbiasz;

  // staging: each instr covers 8 rows x 8 swizzled 16B slots
  const int srow = lane >> 3;
  const int sslot = s7 ^ srow;  // pre-swizzled global 16B slot
  const unsigned short* aS = A + (size_t)(m0 + srow) * lda + sslot * 8;
  const unsigned short* bS = Bt + (size_t)(n0 + srow) * ldb + sslot * 8;
  const int arb = (w >> 2) * 128 + (w & 3) * 16;  // A: + c*64 + {0,8}
  const int brb = (w >> 1) * 64 + (w & 1) * 16;   // B: + c*32 + {0,8}

  const int wmB = wm * 128, wnB = wn * 64;

#define LDSA(buf) (lds + (buf) * 65536)
#define LDSB(buf) (lds + (buf) * 65536 + 32768)

#define STAGE_A(c, kt, buf) do { \
    async_copy16(aS + (size_t)(arb + (c)*64) * lda + (kt),     LDSA(buf) + (arb + (c)*64) * 128); \
    async_copy16(aS + (size_t)(arb + (c)*64 + 8) * lda + (kt), LDSA(buf) + (arb + (c)*64 + 8) * 128); \
  } while (0)
#define STAGE_B(c, kt, buf) do { \
    async_copy16(bS + (size_t)(brb + (c)*32) * ldb + (kt),     LDSB(buf) + (brb + (c)*32) * 128); \
    async_copy16(bS + (size_t)(brb + (c)*32 + 8) * ldb + (kt), LDSB(buf) + (brb + (c)*32 + 8) * 128); \
  } while (0)

#define READ_A(QM, SRC) do { _Pragma("unroll") for (int i = 0; i < 4; ++i) { \
      const int ro = (wmB + (QM)*64 + i*16 + l15) * 128; \
      _Pragma("unroll") for (int kk = 0; kk < 2; ++kk) \
        afr[i][kk] = *(const bf16x8*)((SRC) + ro + (((kk*4 + q) ^ s7) * 16)); } } while (0)
#define READ_B(QN, SRC) do { _Pragma("unroll") for (int j = 0; j < 2; ++j) { \
      const int ro = (wnB + (QN)*32 + j*16 + l15) * 128; \
      _Pragma("unroll") for (int kk = 0; kk < 2; ++kk) \
        bfr[(QN)*2 + j][kk] = *(const bf16x8*)((SRC) + ro + (((kk*4 + q) ^ s7) * 16)); } } while (0)
#define MFMA_Q(QM, QN) do { _Pragma("unroll") for (int i = 0; i < 4; ++i) \
      _Pragma("unroll") for (int j = 0; j < 2; ++j) \
      _Pragma("unroll") for (int kk = 0; kk < 2; ++kk) \
        acc[(QM)*4+i][(QN)*2+j] = __builtin_amdgcn_mfma_f32_16x16x32_bf16( \
            afr[i][kk], bfr[(QN)*2+j][kk], acc[(QM)*4+i][(QN)*2+j], 0, 0, 0); } while (0)

  const int NT = K >> 6;
  f32x4 acc[8][4] = {};
  bf16x8 afr[4][2];   // one A quadrant (A0 between p4-post..p2; A1 p2-post..p4)
  bf16x8 bfr[4][2];   // bfr[0..1]=B-q0 (p4-post..p4), bfr[2..3]=B-q1 (p1..p3)

  // prologue: tile0 full + {A0,B0}(1) [mimics p2(-1),p3(-1)]
  STAGE_A(0, 0, 0); STAGE_A(1, 0, 0);
  STAGE_B(0, 0, 0); STAGE_B(1, 0, 0);
  STAGE_A(0, 64, 1);
  STAGE_B(0, 64, 1);
  asm volatile("s_waitcnt vmcnt(4)" ::: "memory");  // tile0 landed
  __builtin_amdgcn_s_barrier();
  {  // p4(-1)-post: read tile0's A0, B0
    const char* Ab0 = LDSA(0); const char* Bb0 = LDSB(0);
    READ_A(0, Ab0); READ_B(0, Bb0);
  }

  for (int t = 0; t < NT; ++t) {
    const char* Ab  = LDSA(t & 1);
    const char* Bb  = LDSB(t & 1);
    const char* Abn = LDSA((t + 1) & 1);
    const char* Bbn = LDSB((t + 1) & 1);
    const int kt1 = (t + 1) << 6, kt2 = (t + 2) << 6;
    const bool s1 = (t + 1 < NT), s2 = (t + 2 < NT);

    // p1: MFMA(A0,B0); pre-read B1(t); stage A1,B1(t+1)
    READ_B(1, Bb);
    if (s1) { STAGE_A(1, kt1, (t + 1) & 1); STAGE_B(1, kt1, (t + 1) & 1); }
    __builtin_amdgcn_s_barrier();
    __builtin_amdgcn_s_setprio(1); MFMA_Q(0, 0); __builtin_amdgcn_s_setprio(0);
    __builtin_amdgcn_s_barrier();

    // p2: MFMA(A0,B1); post-read A1(t) into freed afr
    if (s2) STAGE_A(0, kt2, t & 1);   // A-q0(t) dead since p4(t-1)
    __builtin_amdgcn_s_barrier();
    __builtin_amdgcn_s_setprio(1); MFMA_Q(0, 1); __builtin_amdgcn_s_setprio(0);
    READ_A(1, Ab);
    __builtin_amdgcn_s_barrier();

    // p3: MFMA(A1,B1); counted vmcnt
    if (s2) STAGE_B(0, kt2, t & 1);   // B-q0(t) dead since p4(t-1)
    __builtin_amdgcn_s_barrier();
    __builtin_amdgcn_s_setprio(1); MFMA_Q(1, 1); __builtin_amdgcn_s_setprio(0);
    if (s2) asm volatile("s_waitcnt vmcnt(4)" ::: "memory");  // tile t+1 all landed
    else    asm volatile("s_waitcnt vmcnt(0)" ::: "memory");  // tail drain
    __builtin_amdgcn_s_barrier();

    // p4: MFMA(A1,B0) all-resident; post-read next tile's A0,B0
    __builtin_amdgcn_s_setprio(1); MFMA_Q(1, 0); __builtin_amdgcn_s_setprio(0);
    if (s1) { READ_A(0, Abn); READ_B(0, Bbn); }
    __builtin_amdgcn_s_barrier();
  }

  // epilogue: C/D frag layout col = lane&15, row = (lane>>4)*4 + reg
  char* Cb = (char*)Cout + (size_t)blockIdx.z * sCz * (OUT_BF16 ? 2 : 4);
#pragma unroll
  for (int mi = 0; mi < 8; ++mi) {
#pragma unroll
    for (int nj = 0; nj < 4; ++nj) {
      const int row0 = m0 + wmB + mi * 16 + q * 4;
      const int col  = n0 + wnB + nj * 16 + l15;
      float cb = (BIAS_MODE == 1) ? bias[col] : 0.0f;
#pragma unroll
      for (int r = 0; r < 4; ++r) {
        float v = acc[mi][nj][r] * alpha + cb;
        if (BIAS_MODE == 2) v += bias[row0 + r];
        const size_t idx = (size_t)(row0 + r) * ldc + col;
        if (OUT_BF16) ((unsigned short*)Cb)[idx] = f2bf(v);
        else          ((float*)Cb)[idx] = v;
      }
    }
  }
#undef LDSA
#undef LDSB
#undef STAGE_A
#undef STAGE_B
#undef READ_A
#undef READ_B
#undef MFMA_Q
}

// ---------------------------------------------------------------------------
// fp32 -> bf16 elementwise convert
// ---------------------------------------------------------------------------
__global__ __launch_bounds__(256) void convert_f32_bf16(
    const float* __restrict__ x, unsigned short* __restrict__ y, int n4)
{
  int i = blockIdx.x * blockDim.x + threadIdx.x;
  const int stride = gridDim.x * blockDim.x;
  for (; i < n4; i += stride) {
    float4 v = ((const float4*)x)[i];
    ushort4 o;
    o.x = f2bf(v.x); o.y = f2bf(v.y); o.z = f2bf(v.z); o.w = f2bf(v.w);
    ((ushort4*)y)[i] = o;
  }
}

// ---------------------------------------------------------------------------
// W[1024][1024] fp32 -> WT[1024][1024] bf16 (transpose)
// ---------------------------------------------------------------------------
__global__ __launch_bounds__(256) void transpose_to_bf16(
    const float* __restrict__ W0, const float* __restrict__ W1, const float* __restrict__ W2,
    unsigned short* __restrict__ T0, unsigned short* __restrict__ T1, unsigned short* __restrict__ T2)
{
  __shared__ float tile[64][65];
  const float* W = (blockIdx.z == 0) ? W0 : (blockIdx.z == 1) ? W1 : W2;
  unsigned short* T = (blockIdx.z == 0) ? T0 : (blockIdx.z == 1) ? T1 : T2;
  const int tx = threadIdx.x;  // 0..63
  const int ty = threadIdx.y;  // 0..3
  const int n0 = blockIdx.x * 64, k0 = blockIdx.y * 64;
#pragma unroll
  for (int r = ty; r < 64; r += 4)
    tile[r][tx] = W[(size_t)(k0 + r) * 1024 + n0 + tx];
  __syncthreads();
#pragma unroll
  for (int r = ty; r < 64; r += 4)
    T[(size_t)(n0 + r) * 1024 + k0 + tx] = f2bf(tile[tx][r]);
}

// ---------------------------------------------------------------------------
// In-place row softmax over bf16 rows of length 4096 (1 block / row)
// ---------------------------------------------------------------------------
__global__ __launch_bounds__(256) void softmax_rows(unsigned short* __restrict__ S, int ncols)
{
  __shared__ float red[8];
  unsigned short* p = S + (size_t)blockIdx.x * ncols;
  const int tid = threadIdx.x;

  u16x8 r0 = ((const u16x8*)p)[tid * 2];
  u16x8 r1 = ((const u16x8*)p)[tid * 2 + 1];
  float v[16];
#pragma unroll
  for (int i = 0; i < 8; ++i) v[i] = bf2f(r0[i]);
#pragma unroll
  for (int i = 0; i < 8; ++i) v[8 + i] = bf2f(r1[i]);

  float m = -1e30f;
#pragma unroll
  for (int i = 0; i < 16; ++i) m = fmaxf(m, v[i]);
#pragma unroll
  for (int off = 32; off; off >>= 1) m = fmaxf(m, __shfl_xor(m, off));
  if ((tid & 63) == 0) red[tid >> 6] = m;
  __syncthreads();
  m = fmaxf(fmaxf(red[0], red[1]), fmaxf(red[2], red[3]));

  float s = 0.0f;
#pragma unroll
  for (int i = 0; i < 16; ++i) {
    v[i] = exp2f((v[i] - m) * 1.44269504088896f);
    s += v[i];
  }
#pragma unroll
  for (int off = 32; off; off >>= 1) s += __shfl_xor(s, off);
  if ((tid & 63) == 0) red[4 + (tid >> 6)] = s;
  __syncthreads();
  s = red[4] + red[5] + red[6] + red[7];
  const float inv = 1.0f / s;

  u16x8 o0, o1;
#pragma unroll
  for (int i = 0; i < 8; ++i) o0[i] = f2bf(v[i] * inv);
#pragma unroll
  for (int i = 0; i < 8; ++i) o1[i] = f2bf(v[8 + i] * inv);
  ((u16x8*)p)[tid * 2] = o0;
  ((u16x8*)p)[tid * 2 + 1] = o1;
}

// ---------------------------------------------------------------------------
// Orchestration. x:[4,4096,1024]f32, W*:[1024,1024]f32, b*:[1024]f32,
// out:[4,4096,1024]f32.
//
// Batched path (ws >= 224 MB):
//   WT @0 (6.29MB) and Xb @6291456 (32MB) sit INSIDE the S_all region (dead
//   after projections). biasQK (8KB f32[2][1024]) @39845888 (also inside).
//   S_all @0 (128MB), Qb @134217728, Kb @167772160, VTb @201326592;
//   total 234,881,024 B.
// Fallback (ws >= 174,063,616 B): per-batch S; separate Q/K projections.
// ---------------------------------------------------------------------------
extern "C" void kernel_launch(void* const* d_in, const int* in_sizes, int n_in,
                              void* d_out, int out_size, void* d_ws, size_t ws_size,
                              hipStream_t stream) {
  (void)in_sizes; (void)n_in; (void)out_size;
  const float* x  = (const float*)d_in[0];
  const float* Wq = (const float*)d_in[1];
  const float* bq = (const float*)d_in[2];
  const float* Wk = (const float*)d_in[3];
  const float* bk = (const float*)d_in[4];
  const float* Wv = (const float*)d_in[5];
  const float* bv = (const float*)d_in[6];
  float* out = (float*)d_out;
  char* ws = (char*)d_ws;

  const bool batched = ws_size >= 234881024ull;

  unsigned short *WqT, *WkT, *WvT, *Xb, *Qb, *Kb, *VTb, *Sall = nullptr, *Sb = nullptr;
  float* biasQK = nullptr;
  if (batched) {
    WqT = (unsigned short*)(ws);
    WkT = WqT + 1048576; WvT = WkT + 1048576;
    Xb  = (unsigned short*)(ws + 6291456);
    biasQK = (float*)(ws + 39845888);
    Sall = (unsigned short*)(ws);
    Qb  = (unsigned short*)(ws + 134217728);
    Kb  = (unsigned short*)(ws + 167772160);
    VTb = (unsigned short*)(ws + 201326592);
  } else {
    WqT = (unsigned short*)(ws);
    WkT = WqT + 1048576; WvT = WkT + 1048576;
    Qb  = (unsigned short*)(ws + 6291456);
    Kb  = (unsigned short*)(ws + 39845888);
    VTb = (unsigned short*)(ws + 73400320);
    Xb  = (unsigned short*)(ws + 106954752);
    Sb  = (unsigned short*)(ws + 140509184);
  }

  // 1) precision conversion / weight transpose
  convert_f32_bf16<<<2048, 256, 0, stream>>>(x, Xb, 4194304);
  transpose_to_bf16<<<dim3(16, 16, 3), dim3(64, 4), 0, stream>>>(Wq, Wk, Wv, WqT, WkT, WvT);

  // 2) projections (K=1024)
  if (batched) {
    hipMemcpyAsync(biasQK,        bq, 4096, hipMemcpyDeviceToDevice, stream);
    hipMemcpyAsync(biasQK + 1024, bk, 4096, hipMemcpyDeviceToDevice, stream);
    // fused Q,K projection: z picks {Wq->Qb, Wk->Kb}, 512 blocks
    gemm256<1, true><<<dim3(4, 64, 2), 512, 0, stream>>>(Xb, WqT, biasQK, Qb,
        1024, 1024, 1024, 1024, 1.0f, 0, 1048576, 16777216, 1024);
  } else {
    gemm256<1, true><<<dim3(4, 64, 1), 512, 0, stream>>>(Xb, WqT, bq, Qb,
        1024, 1024, 1024, 1024, 1.0f, 0, 0, 0, 0);
    gemm256<1, true><<<dim3(4, 64, 1), 512, 0, stream>>>(Xb, WkT, bk, Kb,
        1024, 1024, 1024, 1024, 1.0f, 0, 0, 0, 0);
  }
  // V pre-transposed: VT[h][s] = sum_d WvT[h][d] X[s][d] + bv[h] (row-bias)
  gemm256<2, true><<<dim3(64, 4, 1), 512, 0, stream>>>(WvT, Xb, bv, VTb,
      1024, 1024, 1024, 16384, 1.0f, 0, 0, 0, 0);

  if (batched) {
    // 3) S = Q K^T / 32, all batches (1024 blocks)
    gemm256<0, true><<<dim3(16, 16, 4), 512, 0, stream>>>(Qb, Kb, nullptr, Sall,
        1024, 1024, 1024, 4096, 0.03125f, 4194304, 4194304, 16777216, 0);
    // 4) softmax over all 16384 rows
    softmax_rows<<<16384, 256, 0, stream>>>(Sall, 4096);
    // 5) O = P V, all batches (256 blocks)
    gemm256<0, false><<<dim3(4, 16, 4), 512, 0, stream>>>(Sall, VTb, nullptr, out,
        4096, 4096, 16384, 1024, 1.0f, 16777216, 4096, 4194304, 0);
  } else {
    for (int b = 0; b < 4; ++b) {
      const size_t qoff = (size_t)b * 4194304;
      gemm256<0, true><<<dim3(16, 16, 1), 512, 0, stream>>>(Qb + qoff, Kb + qoff, nullptr, Sb,
          1024, 1024, 1024, 4096, 0.03125f, 0, 0, 0, 0);
      softmax_rows<<<4096, 256, 0, stream>>>(Sb, 4096);
      gemm256<0, false><<<dim3(4, 16, 1), 512, 0, stream>>>(Sb, VTb + (size_t)b * 4096, nullptr, out + qoff,
          4096, 4096, 16384, 1024, 1.0f, 0, 0, 0, 0);
    }
  }
}